// Round 3
// baseline (98.349 us; speedup 1.0000x reference)
//
#include <hip/hip_runtime.h>
#include <hip/hip_bf16.h>

// SlidingGaussianWindow1d: B=16, T=256, C=64, NWIN=224, wsize=32.
// out[b,w,c,d] = corrcoef over t of (W[w,t]*x[b,t,c]), clipped to [-1,1].
//
// Single fused kernel, one (b,w) pair per block (3584 blocks, 256 thr):
//  - normalized smoothed-box window has fixed fp32 support; stage K=64
//    rolled samples [96,160) — exact (zero-weight samples contribute 0;
//    mean/cov use full T=256 denominators).
//  - y^T staged bf16 in LDS; raw Gram via mfma_f32_32x32x16_bf16 (4 waves =
//    2x2 grid of 32x32 tiles); mean correction from quantized column sums.
//  - epilogue factored as corr = G*f_r*f_c - e_r*e_c  (f=rsqrt(V),
//    e=colsum*f/16; the 1/255 cancels). G symmetric => each lane writes its
//    rr-quad TRANSPOSED as one contiguous nontemporal float4.

static constexpr int TT   = 256;   // time samples
static constexpr int CC   = 64;    // channels
static constexpr int NW   = 224;   // windows
static constexpr int KS   = 64;    // staged support length (multiple of 16)
static constexpr int U0   = 96;    // support window start (rolled coord)
static constexpr int KPAD = KS + 8; // LDS row stride: 72 bf16 = 144 B

typedef short bf16x8 __attribute__((ext_vector_type(8)));
typedef float f32x16 __attribute__((ext_vector_type(16)));
typedef float f32x4  __attribute__((ext_vector_type(4)));

__global__ __launch_bounds__(256) void corr_kernel(const float* __restrict__ x,
                                                   const float* __restrict__ alpha,
                                                   float* __restrict__ out) {
    __shared__ float Ed[32];                               // exp(-d^2)*scale
    __shared__ float Wn[KS];                               // window taps
    __shared__ __align__(16) __hip_bfloat16 Yt[CC][KPAD];  // y^T bf16
    __shared__ float red[4][CC];
    __shared__ float colsum[CC];
    __shared__ __align__(16) float fsh[CC];                // rsqrt(V)
    __shared__ __align__(16) float esh[CC];                // colsum*f/16

    const int tid = threadIdx.x;
    const int blk = blockIdx.x;
    const int b = blk / NW;
    const int w = blk - b * NW;
    // cumulative roll S[w] = sum_{k<=w} (k-111) = (w+1)(w-222)/2
    const int S = ((w + 1) * (w - 222)) / 2;

    // --- window weights (alpha scale cancels in the ratio; kept for
    //     faithfulness so degenerate alpha still NaNs like the reference) ---
    if (tid < 25) {
        float a = alpha[0];
        float scale = 1.0f / (2.0f * a * a);
        float d = (float)(tid - 12);
        Ed[tid] = expf(-d * d) * scale;
    }
    __syncthreads();
    if (tid < KS) {
        // A[t] = sum_{j=112..143} E(t-j); A_max = sum_{|d|<=12} E(d)
        float tot = 0.f;
        for (int k = 0; k < 25; ++k) tot += Ed[k];
        int t = U0 + tid;
        int dlo = t - 143, dhi = t - 112;
        if (dlo < -12) dlo = -12;
        if (dhi > 12) dhi = 12;
        float s = 0.f;
        for (int d = dlo; d <= dhi; ++d) s += Ed[d + 12];
        Wn[tid] = s / tot;
    }
    __syncthreads();

    // --- stage y^T: Yt[c][u] = bf16( Wn[u] * x[b][(U0+u-S)&255][c] ) ---
    const float* xb = x + (size_t)b * TT * CC;
    const int c = tid & 63;
    const int q = tid >> 6;
    float csum = 0.f;
#pragma unroll
    for (int it = 0; it < (KS >> 3); ++it) {
        int uu = it * 8 + q * 2;
        int t0 = (U0 + uu - S) & 255;
        int t1 = (U0 + uu + 1 - S) & 255;
        float v0 = xb[t0 * CC + c] * Wn[uu];
        float v1 = xb[t1 * CC + c] * Wn[uu + 1];
        __hip_bfloat16 h0 = __float2bfloat16(v0);
        __hip_bfloat16 h1 = __float2bfloat16(v1);
        // column sums from quantized values -> exact centering of the
        // quantized series (corr diag == 1 up to fp32 rounding)
        csum += __bfloat162float(h0) + __bfloat162float(h1);
        unsigned short us0 = *(unsigned short*)&h0;
        unsigned short us1 = *(unsigned short*)&h1;
        unsigned pk = ((unsigned)us1 << 16) | (unsigned)us0;
        *(unsigned*)&Yt[c][uu] = pk;             // uu even -> 4B aligned
    }
    red[q][c] = csum;
    __syncthreads();
    if (tid < CC) colsum[tid] = red[0][tid] + red[1][tid] + red[2][tid] + red[3][tid];

    // --- Gram via MFMA: G = Y^T Y, 4 waves -> 2x2 grid of 32x32 tiles ---
    const int wv = tid >> 6;
    const int lane = tid & 63;
    const int ti = wv >> 1, tj = wv & 1;
    const int r32 = lane & 31, half = lane >> 5;
    f32x16 acc;
#pragma unroll
    for (int i = 0; i < 16; ++i) acc[i] = 0.f;
    const __hip_bfloat16* arow = &Yt[32 * ti + r32][half * 8];
    const __hip_bfloat16* brow = &Yt[32 * tj + r32][half * 8];
#pragma unroll
    for (int k0 = 0; k0 < KS; k0 += 16) {
        bf16x8 af = *(const bf16x8*)(arow + k0);
        bf16x8 bf = *(const bf16x8*)(brow + k0);
        acc = __builtin_amdgcn_mfma_f32_32x32x16_bf16(af, bf, acc, 0, 0, 0);
    }
    __syncthreads();   // colsum visible; Yt free; accs done

    // --- diag -> f = rsqrt(V), e = colsum*f/16;  V = G_ii - colsum^2/256.
    //     C/D layout: col = lane&31, row = (reg&3)+8*(reg>>2)+4*(lane>>5)
    //     [m74/m101 verified] ---
    if (ti == tj) {
        int needHalf = (r32 >> 2) & 1;
        if (half == needHalf) {
            int reg = ((r32 >> 3) << 2) | (r32 & 3);
            float g = acc[0];
#pragma unroll
            for (int rr = 1; rr < 16; ++rr)
                if (rr == reg) g = acc[rr];
            int cg = 32 * ti + r32;
            float cs = colsum[cg];
            float V = g - cs * cs * (1.0f / 256.0f);
            float f = rsqrtf(fmaxf(V, 1e-38f));
            fsh[cg] = f;
            esh[cg] = cs * f * 0.0625f;
        }
    }
    __syncthreads();

    // --- normalize, clip, store TRANSPOSED (G symmetric => exact):
    //     value G[row][col] written at out[col][row]; the 4 rows of an
    //     rr-quad are contiguous -> one nontemporal float4 per quad. ---
    float* outb = out + (size_t)blk * (CC * CC);
    const int colg = 32 * tj + r32;              // this lane's fixed col
    const float fc = fsh[colg];
    const float ec = esh[colg];
    float* obase = outb + colg * CC + 32 * ti + 4 * half;
#pragma unroll
    for (int g = 0; g < 4; ++g) {
        const int rbase = 32 * ti + 8 * g + 4 * half;
        f32x4 f4 = *(const f32x4*)&fsh[rbase];
        f32x4 e4 = *(const f32x4*)&esh[rbase];
        f32x4 v;
#pragma unroll
        for (int j = 0; j < 4; ++j) {
            float t1 = acc[4 * g + j] * f4[j];
            float cr = t1 * fc - e4[j] * ec;
            v[j] = fminf(1.0f, fmaxf(-1.0f, cr));
        }
        __builtin_nontemporal_store(v, (f32x4*)(obase + 8 * g));
    }
}

extern "C" void kernel_launch(void* const* d_in, const int* in_sizes, int n_in,
                              void* d_out, int out_size, void* d_ws, size_t ws_size,
                              hipStream_t stream) {
    const float* x     = (const float*)d_in[0];
    const float* alpha = (const float*)d_in[1];
    float* out = (float*)d_out;
    (void)d_ws; (void)ws_size;

    corr_kernel<<<16 * NW, 256, 0, stream>>>(x, alpha, out);
}

// Round 4
// 82.239 us; speedup vs baseline: 1.1959x; 1.1959x over previous
//
#include <hip/hip_runtime.h>
#include <hip/hip_bf16.h>

// SlidingGaussianWindow1d: B=16, T=256, C=64, NWIN=224, wsize=32.
// out[b,w,c,d] = corrcoef over t of (W[w,t]*x[b,t,c]), clipped to [-1,1].
//
// Single fused kernel, one (b,w) pair per block (3584 blocks, 256 thr):
//  - normalized smoothed-box window has fixed fp32 support; stage K=64
//    rolled samples [96,160) — exact (zero-weight samples contribute 0;
//    mean/cov use full T=256 denominators).
//  - y^T staged bf16 in LDS (thread = one channel x 16 u's: packed bf16
//    converts + 2x ds_write_b128); raw Gram via mfma_f32_32x32x16_bf16
//    (4 waves = 2x2 grid of 32x32 tiles); mean correction from quantized
//    column sums.
//  - epilogue: corr = G*f_r*f_c - e_r*e_c (f=rsqrt(V), e=colsum*f/16; the
//    1/255 cancels), f/e via broadcast ds_read_b128 quads, stores in the
//    R2 COALESCED pattern (per-instr: 2x128B contiguous), nontemporal.
//    (R3 lesson: transposed float4 stores scatter 16B chunks 256B apart
//    across lanes -> ~2x kernel regression. Keep lane-contiguous stores.)

static constexpr int TT   = 256;   // time samples
static constexpr int CC   = 64;    // channels
static constexpr int NW   = 224;   // windows
static constexpr int KS   = 64;    // staged support length (multiple of 16)
static constexpr int U0   = 96;    // support window start (rolled coord)
static constexpr int KPAD = KS + 8; // LDS row stride: 72 bf16 = 144 B

typedef short bf16x8 __attribute__((ext_vector_type(8)));
typedef float f32x16 __attribute__((ext_vector_type(16)));
typedef float f32x4  __attribute__((ext_vector_type(4)));

__global__ __launch_bounds__(256) void corr_kernel(const float* __restrict__ x,
                                                   const float* __restrict__ alpha,
                                                   float* __restrict__ out) {
    __shared__ float Ed[32];                               // exp(-d^2)*scale
    __shared__ float Wn[KS];                               // window taps
    __shared__ __align__(16) __hip_bfloat16 Yt[CC][KPAD];  // y^T bf16
    __shared__ float red[4][CC];
    __shared__ float colsum[CC];
    __shared__ __align__(16) float fsh[CC];                // rsqrt(V)
    __shared__ __align__(16) float esh[CC];                // colsum*f/16

    const int tid = threadIdx.x;
    const int blk = blockIdx.x;
    const int b = blk / NW;
    const int w = blk - b * NW;
    // cumulative roll S[w] = sum_{k<=w} (k-111) = (w+1)(w-222)/2
    const int S = ((w + 1) * (w - 222)) / 2;

    // --- window weights (alpha scale cancels in the ratio; kept for
    //     faithfulness so degenerate alpha still NaNs like the reference) ---
    if (tid < 25) {
        float a = alpha[0];
        float scale = 1.0f / (2.0f * a * a);
        float d = (float)(tid - 12);
        Ed[tid] = expf(-d * d) * scale;
    }
    __syncthreads();
    if (tid < KS) {
        // A[t] = sum_{j=112..143} E(t-j); A_max = sum_{|d|<=12} E(d)
        float tot = 0.f;
        for (int k = 0; k < 25; ++k) tot += Ed[k];
        int t = U0 + tid;
        int dlo = t - 143, dhi = t - 112;
        if (dlo < -12) dlo = -12;
        if (dhi > 12) dhi = 12;
        float s = 0.f;
        for (int d = dlo; d <= dhi; ++d) s += Ed[d + 12];
        Wn[tid] = s / tot;
    }
    __syncthreads();

    // --- stage y^T: Yt[c][u] = bf16( Wn[u] * x[b][(U0+u-S)&255][c] ).
    //     Thread = (channel c, u-range [16q,16q+16)); loads are lane-
    //     coalesced dwords (c contiguous); packed cvt + 2x ds_write_b128. ---
    const float* xb = x + (size_t)b * TT * CC;
    const int c = tid & 63;
    const int q = tid >> 6;
    const int ub = 16 * q;
    const int tb = U0 + ub - S;
    float csum = 0.f;
    int4 w0, w1;
#pragma unroll
    for (int jp = 0; jp < 8; ++jp) {
        int u  = ub + 2 * jp;
        int t0 = (tb + 2 * jp) & 255;
        int t1 = (tb + 2 * jp + 1) & 255;
        float v0 = xb[t0 * CC + c] * Wn[u];
        float v1 = xb[t1 * CC + c] * Wn[u + 1];
        __hip_bfloat162 h2 = __float22bfloat162_rn(make_float2(v0, v1));
        // column sums from the quantized values -> exact centering of the
        // quantized series (corr diag == 1 up to fp32 rounding)
        float2 qf = __bfloat1622float2(h2);
        csum += qf.x + qf.y;
        unsigned pu;
        __builtin_memcpy(&pu, &h2, 4);
        if (jp < 4) ((unsigned*)&w0)[jp] = pu;
        else        ((unsigned*)&w1)[jp - 4] = pu;
    }
    *(int4*)&Yt[c][ub]     = w0;   // 144B row stride: both 16B-aligned
    *(int4*)&Yt[c][ub + 8] = w1;
    red[q][c] = csum;
    __syncthreads();
    if (tid < CC) colsum[tid] = red[0][tid] + red[1][tid] + red[2][tid] + red[3][tid];

    // --- Gram via MFMA: G = Y^T Y, 4 waves -> 2x2 grid of 32x32 tiles ---
    const int wv = tid >> 6;
    const int lane = tid & 63;
    const int ti = wv >> 1, tj = wv & 1;
    const int r32 = lane & 31, half = lane >> 5;
    f32x16 acc;
#pragma unroll
    for (int i = 0; i < 16; ++i) acc[i] = 0.f;
    const __hip_bfloat16* arow = &Yt[32 * ti + r32][half * 8];
    const __hip_bfloat16* brow = &Yt[32 * tj + r32][half * 8];
#pragma unroll
    for (int k0 = 0; k0 < KS; k0 += 16) {
        bf16x8 af = *(const bf16x8*)(arow + k0);
        bf16x8 bf = *(const bf16x8*)(brow + k0);
        acc = __builtin_amdgcn_mfma_f32_32x32x16_bf16(af, bf, acc, 0, 0, 0);
    }
    __syncthreads();   // colsum visible; accs done

    // --- diag -> f = rsqrt(V), e = colsum*f/16;  V = G_ii - colsum^2/256.
    //     C/D layout: col = lane&31, row = (reg&3)+8*(reg>>2)+4*(lane>>5)
    //     [m74/m101 verified] ---
    if (ti == tj) {
        int needHalf = (r32 >> 2) & 1;
        if (half == needHalf) {
            int reg = ((r32 >> 3) << 2) | (r32 & 3);
            float g = acc[0];
#pragma unroll
            for (int rr = 1; rr < 16; ++rr)
                if (rr == reg) g = acc[rr];
            int cg = 32 * ti + r32;
            float cs = colsum[cg];
            float V = g - cs * cs * (1.0f / 256.0f);
            float f = rsqrtf(fmaxf(V, 1e-38f));
            fsh[cg] = f;
            esh[cg] = cs * f * 0.0625f;
        }
    }
    __syncthreads();

    // --- normalize, clip, store (R2 coalesced pattern + nontemporal):
    //     per store instr: half 0 lanes -> 32 contiguous dwords of one row,
    //     half 1 lanes -> 32 contiguous dwords of another row. ---
    float* outb = out + (size_t)blk * (CC * CC);
    const int colg = 32 * tj + r32;
    const float fc = fsh[colg];
    const float ec = esh[colg];
#pragma unroll
    for (int g = 0; g < 4; ++g) {
        const int rbase = 32 * ti + 8 * g + 4 * half;   // 16B-aligned idx
        f32x4 f4 = *(const f32x4*)&fsh[rbase];          // broadcast b128
        f32x4 e4 = *(const f32x4*)&esh[rbase];
#pragma unroll
        for (int j = 0; j < 4; ++j) {
            float cr = acc[4 * g + j] * f4[j] * fc - e4[j] * ec;
            cr = fminf(1.0f, fmaxf(-1.0f, cr));
            __builtin_nontemporal_store(cr, outb + (rbase + j) * CC + colg);
        }
    }
}

extern "C" void kernel_launch(void* const* d_in, const int* in_sizes, int n_in,
                              void* d_out, int out_size, void* d_ws, size_t ws_size,
                              hipStream_t stream) {
    const float* x     = (const float*)d_in[0];
    const float* alpha = (const float*)d_in[1];
    float* out = (float*)d_out;
    (void)d_ws; (void)ws_size;

    corr_kernel<<<16 * NW, 256, 0, stream>>>(x, alpha, out);
}

// Round 5
// 80.819 us; speedup vs baseline: 1.2169x; 1.0176x over previous
//
#include <hip/hip_runtime.h>
#include <hip/hip_bf16.h>

// SlidingGaussianWindow1d: B=16, T=256, C=64, NWIN=224, wsize=32.
// out[b,w,c,d] = corrcoef over t of (W[w,t]*x[b,t,c]), clipped to [-1,1].
//
// Single fused kernel, one (b,w) pair per block (3584 blocks, 256 thr):
//  - normalized smoothed-box window has fixed fp32 support; stage K=64
//    rolled samples [96,160) — exact (zero-weight samples contribute 0;
//    mean/cov use full T=256 denominators).
//  - y^T staged bf16 in LDS; raw Gram via mfma_f32_32x32x16_bf16 (4 waves =
//    2x2 grid of 32x32 tiles); mean correction from quantized column sums.
//  - epilogue: corr = G*f_r*f_c - e_r*e_c (f=rsqrt(V), e=colsum*f/16; the
//    1/255 cancels). Values round-trip through an LDS Cmat (unioned with
//    the dead Yt buffer) so global stores are flat-contiguous float4
//    nontemporal (1KB per wave-instruction, 4 store issues/thread vs 16).
//    (R3 lesson: never let lanes' store addresses stride by 256B.)

static constexpr int TT   = 256;   // time samples
static constexpr int CC   = 64;    // channels
static constexpr int NW   = 224;   // windows
static constexpr int KS   = 64;    // staged support length (multiple of 16)
static constexpr int U0   = 96;    // support window start (rolled coord)
static constexpr int KPAD = KS + 8; // Yt row stride: 72 bf16 = 144 B

typedef short bf16x8 __attribute__((ext_vector_type(8)));
typedef float f32x16 __attribute__((ext_vector_type(16)));
typedef float f32x4  __attribute__((ext_vector_type(4)));

__global__ __launch_bounds__(256) void corr_kernel(const float* __restrict__ x,
                                                   const float* __restrict__ alpha,
                                                   float* __restrict__ out) {
    __shared__ float Ed[32];                        // exp(-d^2)*scale
    __shared__ float Wn[KS];                        // window taps
    // union: Yt (64x72 bf16 = 9216B) while staging/MFMA; Cmat (64x64 f32 =
    // 16384B) after the post-MFMA barrier.
    __shared__ __align__(16) char uni[CC * CC * 4];
    __shared__ float red[4][CC];
    __shared__ float colsum[CC];
    __shared__ __align__(16) float fsh[CC];         // rsqrt(V)
    __shared__ __align__(16) float esh[CC];         // colsum*f/16

    auto Yt = (__hip_bfloat16(*)[KPAD])uni;
    float* Cmat = (float*)uni;

    const int tid = threadIdx.x;
    const int blk = blockIdx.x;
    const int b = blk / NW;
    const int w = blk - b * NW;
    // cumulative roll S[w] = sum_{k<=w} (k-111) = (w+1)(w-222)/2
    const int S = ((w + 1) * (w - 222)) / 2;

    // --- window weights (alpha scale cancels in the ratio; kept for
    //     faithfulness so degenerate alpha still NaNs like the reference) ---
    if (tid < 25) {
        float a = alpha[0];
        float scale = 1.0f / (2.0f * a * a);
        float d = (float)(tid - 12);
        Ed[tid] = expf(-d * d) * scale;
    }
    __syncthreads();
    if (tid < KS) {
        // A[t] = sum_{j=112..143} E(t-j); A_max = sum_{|d|<=12} E(d)
        float tot = 0.f;
        for (int k = 0; k < 25; ++k) tot += Ed[k];
        int t = U0 + tid;
        int dlo = t - 143, dhi = t - 112;
        if (dlo < -12) dlo = -12;
        if (dhi > 12) dhi = 12;
        float s = 0.f;
        for (int d = dlo; d <= dhi; ++d) s += Ed[d + 12];
        Wn[tid] = s / tot;
    }
    __syncthreads();

    // --- stage y^T: Yt[c][u] = bf16( Wn[u] * x[b][(U0+u-S)&255][c] ).
    //     Thread = (channel c, u-range [16q,16q+16)); lane-coalesced dword
    //     loads (c contiguous); packed cvt + 2x ds_write_b128. ---
    const float* xb = x + (size_t)b * TT * CC;
    const int c = tid & 63;
    const int q = tid >> 6;
    const int ub = 16 * q;
    const int tb = U0 + ub - S;
    float csum = 0.f;
    int4 w0, w1;
#pragma unroll
    for (int jp = 0; jp < 8; ++jp) {
        int u  = ub + 2 * jp;
        int t0 = (tb + 2 * jp) & 255;
        int t1 = (tb + 2 * jp + 1) & 255;
        float v0 = xb[t0 * CC + c] * Wn[u];
        float v1 = xb[t1 * CC + c] * Wn[u + 1];
        __hip_bfloat162 h2 = __float22bfloat162_rn(make_float2(v0, v1));
        // column sums from the quantized values -> exact centering of the
        // quantized series (corr diag == 1 up to fp32 rounding)
        float2 qf = __bfloat1622float2(h2);
        csum += qf.x + qf.y;
        unsigned pu;
        __builtin_memcpy(&pu, &h2, 4);
        if (jp < 4) ((unsigned*)&w0)[jp] = pu;
        else        ((unsigned*)&w1)[jp - 4] = pu;
    }
    *(int4*)&Yt[c][ub]     = w0;   // 144B row stride: both 16B-aligned
    *(int4*)&Yt[c][ub + 8] = w1;
    red[q][c] = csum;
    __syncthreads();
    if (tid < CC) colsum[tid] = red[0][tid] + red[1][tid] + red[2][tid] + red[3][tid];

    // --- Gram via MFMA: G = Y^T Y, 4 waves -> 2x2 grid of 32x32 tiles ---
    const int wv = tid >> 6;
    const int lane = tid & 63;
    const int ti = wv >> 1, tj = wv & 1;
    const int r32 = lane & 31, half = lane >> 5;
    f32x16 acc;
#pragma unroll
    for (int i = 0; i < 16; ++i) acc[i] = 0.f;
    const __hip_bfloat16* arow = &Yt[32 * ti + r32][half * 8];
    const __hip_bfloat16* brow = &Yt[32 * tj + r32][half * 8];
#pragma unroll
    for (int k0 = 0; k0 < KS; k0 += 16) {
        bf16x8 af = *(const bf16x8*)(arow + k0);
        bf16x8 bf = *(const bf16x8*)(brow + k0);
        acc = __builtin_amdgcn_mfma_f32_32x32x16_bf16(af, bf, acc, 0, 0, 0);
    }
    __syncthreads();   // colsum visible; all Yt reads done (Cmat may reuse uni)

    // --- diag -> f = rsqrt(V), e = colsum*f/16;  V = G_ii - colsum^2/256.
    //     C/D layout: col = lane&31, row = (reg&3)+8*(reg>>2)+4*(lane>>5)
    //     [m74/m101 verified] ---
    if (ti == tj) {
        int needHalf = (r32 >> 2) & 1;
        if (half == needHalf) {
            int reg = ((r32 >> 3) << 2) | (r32 & 3);
            float g = acc[0];
#pragma unroll
            for (int rr = 1; rr < 16; ++rr)
                if (rr == reg) g = acc[rr];
            int cg = 32 * ti + r32;
            float cs = colsum[cg];
            float V = g - cs * cs * (1.0f / 256.0f);
            float f = rsqrtf(fmaxf(V, 1e-38f));
            fsh[cg] = f;
            esh[cg] = cs * f * 0.0625f;
        }
    }
    __syncthreads();

    // --- normalize, clip, deposit into LDS Cmat at C/D-layout positions.
    //     Per rr: half-wave writes 32 consecutive dwords of one row ->
    //     conflict-free. ---
    const int colg = 32 * tj + r32;
    const float fc = fsh[colg];
    const float ec = esh[colg];
#pragma unroll
    for (int g = 0; g < 4; ++g) {
        const int rbase = 32 * ti + 8 * g + 4 * half;   // 16B-aligned idx
        f32x4 f4 = *(const f32x4*)&fsh[rbase];          // broadcast b128
        f32x4 e4 = *(const f32x4*)&esh[rbase];
#pragma unroll
        for (int j = 0; j < 4; ++j) {
            float cr = acc[4 * g + j] * f4[j] * fc - e4[j] * ec;
            cr = fminf(1.0f, fmaxf(-1.0f, cr));
            Cmat[(rbase + j) * CC + colg] = cr;
        }
    }
    __syncthreads();

    // --- stream out: flat-contiguous float4 nontemporal stores; each wave
    //     instruction writes 1KB fully contiguous. ---
    float* outb = out + (size_t)blk * (CC * CC);
#pragma unroll
    for (int pass = 0; pass < 4; ++pass) {
        int fidx = pass * 1024 + tid * 4;
        f32x4 v = *(const f32x4*)(Cmat + fidx);
        __builtin_nontemporal_store(v, (f32x4*)(outb + fidx));
    }
}

extern "C" void kernel_launch(void* const* d_in, const int* in_sizes, int n_in,
                              void* d_out, int out_size, void* d_ws, size_t ws_size,
                              hipStream_t stream) {
    const float* x     = (const float*)d_in[0];
    const float* alpha = (const float*)d_in[1];
    float* out = (float*)d_out;
    (void)d_ws; (void)ws_size;

    corr_kernel<<<16 * NW, 256, 0, stream>>>(x, alpha, out);
}